// Round 6
// baseline (263.600 us; speedup 1.0000x reference)
//
#include <hip/hip_runtime.h>

#define BB     128
#define MM     4096
#define NN     8192
#define DEG    12
#define RDEG   11         // edge 11 is ALWAYS the dummy (col==NN) -> hardcoded
#define MAXIT  8
#define BLOCK  1024
#define RPT    (MM / BLOCK)
#define NW     (NN / 2)   // l_v packed: 2 vars per word, u16 halves biased +32768
#define BIAS   32768
#define BIG    (1 << 20)

__device__ __forceinline__ int quantI(float x) {   // fp2fxp -> units of 1/16 (RNE)
    float r = rintf(x * 16.0f);
    r = fminf(r, 127.0f);
    r = fmaxf(r, -128.0f);
    return (int)r;
}
__device__ __forceinline__ int clamp8(int t) { return max(-128, min(127, t)); }
__device__ __forceinline__ int rne4(int t) {       // RNE of t/16, t >= 0
    const int r = t >> 4, rem = t & 15;
    return r + (((rem > 8) || (rem == 8 && (r & 1))) ? 1 : 0);
}

// One flooding iteration. cur/oth are __restrict__ so the compiler knows the
// gathers (cur) cannot alias the delta-atomics (oth): row k+1's ds_read_u16
// can issue above row k's ds_atomic_add -> cross-row pipelining without any
// extra live registers. Columns are re-read from global (L2-resident) each
// call; global loads hoist freely over LDS ops (separate vmcnt pipe).
template<bool FIRST>
__device__ __forceinline__ int iterBody(const int fbI, const bool fb1,
                                        const int* __restrict__ Vc,
                                        const unsigned short* __restrict__ curS,
                                        int* __restrict__ oth,
                                        unsigned* __restrict__ msgp,
                                        unsigned* __restrict__ msg2p,
                                        const int syn)
{
    int mism = 0;
    #pragma unroll
    for (int k = 0; k < RPT; ++k) {
        const int4* cp = (const int4*)(Vc + (size_t)k * (BLOCK * DEG));
        const int4 c0 = cp[0], c1 = cp[1], c2 = cp[2];
        const int cc[RDEG] = {c0.x,c0.y,c0.z,c0.w,c1.x,c1.y,c1.z,c1.w,c2.x,c2.y,c2.z};

        int a[RDEG];
        int par = 0, sbits = 0;
        int min0 = BIG, min1 = BIG;
        #pragma unroll
        for (int d = 0; d < RDEG; ++d) {
            const int lu = (int)curS[cc[d]];
            const int m  = (int)(signed char)((msgp[3*k + (d >> 2)] >> ((d & 3) * 8)) & 0xffu);
            par ^= (lu <= BIAS) ? 1 : 0;                  // l_v <= 0
            const int av = clamp8((lu - BIAS) - m);       // it=1: m=0, l=u0 -> a=message0
            a[d] = av;
            const int aa = abs(av);
            sbits |= ((av <= 0) ? 1 : 0) << d;            // sign(0) -> -1
            min1 = min(min1, max(min0, aa));
            min0 = min(min0, aa);
        }
        if (!FIRST) {
            // dummy edge: a = fxp(inf-0) = 7.9375 -> 127, sign +, joins the mins
            min1 = min(min1, max(min0, 127));
            min0 = min(min0, 127);
            mism |= par ^ ((syn >> k) & 1);
        }
        const int qsb = ((syn >> k) & 1) ^ (__popc(sbits) & 1);  // 1 => flip sign
        const int m0C = min(min0, 127), m1C = min(min1, 127);
        const int q0  = fb1 ? m0C : rne4(m0C * fbI);      // per-row magnitudes
        const int q1  = fb1 ? m1C : rne4(m1C * fbI);

        unsigned nm0 = 0u, nm1 = 0u, nm2 = 0u;
        #pragma unroll
        for (int d = 0; d < RDEG; ++d) {
            const int q  = (abs(a[d]) == min0) ? q1 : q0;
            const int s  = ((sbits >> d) & 1) ^ qsb;
            const int bv = s ? -q : q;
            if (d < 4)      nm0 |= ((unsigned)bv & 0xffu) << (d * 8);
            else if (d < 8) nm1 |= ((unsigned)bv & 0xffu) << ((d - 4) * 8);
            else            nm2 |= ((unsigned)bv & 0xffu) << ((d - 8) * 8);
            const int old2 = (int)(signed char)((msg2p[3*k + (d >> 2)] >> ((d & 3) * 8)) & 0xffu);
            const int dl = bv - old2;                     // b_it - b_{it-2}
            if (dl != 0) {
                const int col = cc[d];
                atomicAdd(&oth[col >> 1], (int)((unsigned)dl << ((col & 1) << 4)));
            }
        }
        msg2p[3*k + 0] = msgp[3*k + 0];
        msg2p[3*k + 1] = msgp[3*k + 1];
        msg2p[3*k + 2] = msgp[3*k + 2];
        msgp[3*k + 0]  = nm0;
        msgp[3*k + 1]  = nm1;
        msgp[3*k + 2]  = nm2;
    }
    return mism;
}

__global__ __launch_bounds__(BLOCK)
void ldpc_kernel(const float* __restrict__ synd,
                 const float* __restrict__ llr0,
                 const int*  __restrict__ Vcol,
                 float* __restrict__ out)
{
    __shared__ int lvA[NW];      // 16 KB
    __shared__ int lvB[NW];      // 16 KB
    __shared__ int lastbad;

    const int b   = blockIdx.x;
    const int tid = threadIdx.x;
    const float* llr_b  = llr0 + (size_t)b * NN;
    const float* synd_b = synd + (size_t)b * MM;
    const int*   Vc     = Vcol + (size_t)tid * DEG;

    // ---- syndrome bits (4 rows/thread) ----
    int syn = 0;
    #pragma unroll
    for (int k = 0; k < RPT; ++k)
        syn |= ((synd_b[tid + k * BLOCK] != 0.0f) ? 1 : 0) << k;

    // ---- init BOTH buffers to u0; msg history = 0 (it=1 gather == message0) ----
    #pragma unroll
    for (int j = 0; j < 4; ++j) {
        const int w = tid + j * BLOCK;
        float2 f = ((const float2*)llr_b)[w];
        const int pw = (quantI(f.x) + BIAS) | ((quantI(f.y) + BIAS) << 16);
        lvA[w] = pw; lvB[w] = pw;
    }
    if (tid == 0) lastbad = 1;

    unsigned msgp[3 * RPT];    // b_{it-1}, packed s8
    unsigned msg2p[3 * RPT];   // b_{it-2}, packed s8
    #pragma unroll
    for (int p = 0; p < 3 * RPT; ++p) { msgp[p] = 0u; msg2p[p] = 0u; }

    __syncthreads();

    // ---- it = 1: gather lvA (=u0), scatter b1 into lvB (=u0 -> l_v(1)) ----
    iterBody<true>(8, false, Vc, (const unsigned short*)lvA, lvB, msgp, msg2p, syn);
    __syncthreads();

    int* cur = lvB;   // l_v(it-1)
    int* oth = lvA;   // l_v(it-2) -> becomes l_v(it) via delta scatter
    int conv_it = 0;
    const int* outP = nullptr;

    #pragma unroll 1
    for (int it = 2; it <= MAXIT; ++it) {
        const int  fbI = (it == 2) ? 12 : (it == 3) ? 14 : 15;
        const bool fb1 = (it >= 5);
        const int mism = iterBody<false>(fbI, fb1, Vc, (const unsigned short*)cur,
                                         oth, msgp, msg2p, syn);
        if (__any(mism) && (tid & 63) == 0) atomicMax(&lastbad, it);
        __syncthreads();   // scatters into oth done + lastbad settled
        if (lastbad < it) { conv_it = it - 1; outP = cur; break; }  // cur == l_v(it-1)
        int* t = cur; cur = oth; oth = t;
    }

    // ---- if never converged in-loop, check parity of l_v(8) (now in cur) ----
    if (conv_it == 0) {
        const unsigned short* curS = (const unsigned short*)cur;
        int mism = 0;
        #pragma unroll
        for (int k = 0; k < RPT; ++k) {
            const int4* cp = (const int4*)(Vc + (size_t)k * (BLOCK * DEG));
            const int4 c0 = cp[0], c1 = cp[1], c2 = cp[2];
            const int cc[RDEG] = {c0.x,c0.y,c0.z,c0.w,c1.x,c1.y,c1.z,c1.w,c2.x,c2.y,c2.z};
            int par = 0;
            #pragma unroll
            for (int d = 0; d < RDEG; ++d)
                par ^= (curS[cc[d]] <= BIAS) ? 1 : 0;
            mism |= par ^ ((syn >> k) & 1);
        }
        if (__any(mism) && (tid & 63) == 0) atomicMax(&lastbad, MAXIT + 1);
        __syncthreads();
        if (lastbad < MAXIT + 1) conv_it = MAXIT;
        outP = cur;
    }

    // ---- outputs: [e_out | num_iters | l_out | converges], float32 flat ----
    const int   num = conv_it ? conv_it : MAXIT;
    const float cv  = conv_it ? 1.0f : 0.0f;
    float* e_out   = out;
    float* num_out = out + (size_t)BB * NN;
    float* l_out   = num_out + BB;
    float* c_out   = l_out + (size_t)BB * NN;
    #pragma unroll
    for (int j = 0; j < 4; ++j) {
        const int w  = tid + j * BLOCK;
        const int wv = outP[w];
        const int l0 = (wv & 0xffff) - BIAS;
        const int l1 = ((wv >> 16) & 0xffff) - BIAS;
        float2 e, l;
        e.x = (l0 <= 0) ? 1.0f : 0.0f;
        e.y = (l1 <= 0) ? 1.0f : 0.0f;
        l.x = (float)clamp8(l0) * 0.0625f;
        l.y = (float)clamp8(l1) * 0.0625f;
        ((float2*)(e_out + (size_t)b * NN))[w] = e;
        ((float2*)(l_out + (size_t)b * NN))[w] = l;
    }
    if (tid == 0) { num_out[b] = (float)num; c_out[b] = cv; }
}

extern "C" void kernel_launch(void* const* d_in, const int* in_sizes, int n_in,
                              void* d_out, int out_size, void* d_ws, size_t ws_size,
                              hipStream_t stream) {
    (void)in_sizes; (void)n_in; (void)d_ws; (void)ws_size; (void)out_size;
    const float* synd = (const float*)d_in[0];
    const float* llr0 = (const float*)d_in[1];
    const int*   Vcol = (const int*)d_in[3];   // V_c_col
    float*       out  = (float*)d_out;
    ldpc_kernel<<<BB, BLOCK, 0, stream>>>(synd, llr0, Vcol, out);
}

// Round 7
// 141.532 us; speedup vs baseline: 1.8625x; 1.8625x over previous
//
#include <hip/hip_runtime.h>

#define BB     128
#define MM     4096
#define NN     8192
#define DEG    12
#define RDEG   11          // edges 0..10 real; edge 11 is ALWAYS the dummy (col==NN)
#define MAXIT  8
#define BLOCK  1024
#define RPT    (MM / BLOCK)
#define NW     (NN / 2)    // l_v packed: 2 vars per 32-bit word, u16 halves biased +32768
#define BIAS   32768
#define BIG    (1 << 20)

__device__ __forceinline__ int quantI(float x) {   // fp2fxp -> integer units of 1/16
    float r = rintf(x * 16.0f);                    // RNE, matches jnp.round
    r = fminf(r, 127.0f);
    r = fmaxf(r, -128.0f);
    return (int)r;
}
__device__ __forceinline__ int clamp8(int t) { return max(-128, min(127, t)); }
__device__ __forceinline__ int rne4(int t) {       // RNE of t/16, t >= 0
    const int r = t >> 4, rem = t & 15;
    return r + (((rem > 8) || (rem == 8 && (r & 1))) ? 1 : 0);
}

__global__ __launch_bounds__(BLOCK, 4)
__attribute__((amdgpu_waves_per_eu(4, 4)))
void ldpc_kernel(const float* __restrict__ synd,
                 const float* __restrict__ llr0,
                 const int*  __restrict__ Vcol,
                 float* __restrict__ out)
{
    __shared__ int lvbuf[3][NW];   // 48 KB: cur / nxt / rst rotation
    __shared__ int lastbad;

    const int b   = blockIdx.x;
    const int tid = threadIdx.x;
    const float* llr_b  = llr0 + (size_t)b * NN;
    const float* synd_b = synd + (size_t)b * MM;

    // ---- persistent register state (~41 regs; fits the 64-VGPR cap spill-free) ----
    unsigned colp[RPT][6];    // 11 cols packed 2 x u16 (high half of [5] unused)
    int synbits = 0;

    #pragma unroll
    for (int k = 0; k < RPT; ++k) {
        const int row = tid + k * BLOCK;
        const int4* cp = (const int4*)(Vcol + (size_t)row * DEG);
        int4 c0 = cp[0], c1 = cp[1], c2 = cp[2];
        const int cc[RDEG] = {c0.x,c0.y,c0.z,c0.w,c1.x,c1.y,c1.z,c1.w,c2.x,c2.y,c2.z};
        #pragma unroll
        for (int p = 0; p < 5; ++p)
            colp[k][p] = (unsigned)cc[2*p] | ((unsigned)cc[2*p+1] << 16);
        colp[k][5] = (unsigned)cc[10];
        synbits |= ((synd_b[row] != 0.0f) ? 1 : 0) << k;
    }

    // ---- u0 in 4 named scalars (no array -> no scratch risk); thread owns words 4t..4t+3
    int u0a, u0b, u0c, u0d;
    {
        const float2* lp = (const float2*)llr_b;
        float2 f0 = lp[4*tid+0], f1 = lp[4*tid+1], f2 = lp[4*tid+2], f3 = lp[4*tid+3];
        u0a = (quantI(f0.x) + BIAS) | ((quantI(f0.y) + BIAS) << 16);
        u0b = (quantI(f1.x) + BIAS) | ((quantI(f1.y) + BIAS) << 16);
        u0c = (quantI(f2.x) + BIAS) | ((quantI(f2.y) + BIAS) << 16);
        u0d = (quantI(f3.x) + BIAS) | ((quantI(f3.y) + BIAS) << 16);
        ((int4*)lvbuf[1])[tid] = make_int4(u0a, u0b, u0c, u0d);   // it=1 scatter target
    }
    if (tid == 0) lastbad = 1;

    // ---- msg init: message0 = u0[col], one-time scattered global gather (L2-resident)
    unsigned msgp[RPT][3];    // 11 messages packed s8 (byte 3 of [2] unused)
    #pragma unroll
    for (int k = 0; k < RPT; ++k) {
        unsigned nm[3] = {0u, 0u, 0u};
        #pragma unroll
        for (int d = 0; d < RDEG; ++d) {
            const int col = (int)((colp[k][d >> 1] >> ((d & 1) * 16)) & 0xffffu);
            const int m = quantI(llr_b[col]);
            nm[d >> 2] |= ((unsigned)m & 0xffu) << ((d & 3) * 8);
        }
        msgp[k][0] = nm[0]; msgp[k][1] = nm[1]; msgp[k][2] = nm[2];
    }
    __syncthreads();

    int* cur = lvbuf[0];   // unused at it==1
    int* nxt = lvbuf[1];   // holds u0
    int* rst = lvbuf[2];

    int conv_it = 0;
    int it = 1;
    for (; it <= MAXIT; ++it) {
        const int  fbI = (it==1) ? 8 : (it==2) ? 12 : (it==3) ? 14 : 15;
        const bool fb1 = (it >= 5);    // fp2fxp(beta) == 1.0
        int mism = 0;

        #pragma unroll
        for (int k = 0; k < RPT; ++k) {
            int aa[RDEG];                      // |a| (sign lives in sbits)
            int sbits = 0;
            int min0 = BIG, min1 = BIG;
            int par = 0;
            #pragma unroll
            for (int d = 0; d < RDEG; ++d) {
                const int col = (int)((colp[k][d >> 1] >> ((d & 1) * 16)) & 0xffffu);
                const int m = (int)(signed char)((msgp[k][d >> 2] >> ((d & 3) * 8)) & 0xffu);
                int aval;
                if (it == 1) {
                    aval = m;                              // a = message0
                } else {
                    const int w = cur[col >> 1];
                    const int l = (int)((w >> ((col & 1) << 4)) & 0xffff) - BIAS;
                    par ^= (l <= 0) ? 1 : 0;               // parity of l_v(it-1)
                    aval = clamp8(l - m);
                }
                const int av = abs(aval);
                sbits |= ((aval <= 0) ? 1 : 0) << d;       // sign(0) -> -1
                min1 = min(min1, max(min0, av));
                min0 = min(min0, av);
                aa[d] = av;
            }
            if (it > 1) {
                // dummy edge: a = fxp(inf - 0) = 7.9375 -> 127, sign +, joins the mins
                min1 = min(min1, max(min0, 127));
                min0 = min(min0, 127);
                mism |= par ^ ((synbits >> k) & 1);
            }
            // (it==1: dummy a = +inf -> no min participation, sign +)
            const int negs = __popc(sbits) & 1;
            const int qsb  = ((synbits >> k) & 1) ^ negs;  // 1 => flip sign
            const int m0C = min(min0, 127), m1C = min(min1, 127);
            const int q0  = fb1 ? m0C : rne4(m0C * fbI);   // per-row magnitudes
            const int q1  = fb1 ? m1C : rne4(m1C * fbI);

            unsigned nm0 = 0u, nm1 = 0u, nm2 = 0u;
            #pragma unroll
            for (int d = 0; d < RDEG; ++d) {
                const int q  = (aa[d] == min0) ? q1 : q0;
                const int s  = ((sbits >> d) & 1) ^ qsb;
                const int bv = s ? -q : q;
                if (d < 4)      nm0 |= ((unsigned)bv & 0xffu) << (d * 8);
                else if (d < 8) nm1 |= ((unsigned)bv & 0xffu) << ((d - 4) * 8);
                else            nm2 |= ((unsigned)bv & 0xffu) << ((d - 8) * 8);
                if (bv != 0) {                             // zero adds nothing
                    const int col = (int)((colp[k][d >> 1] >> ((d & 1) * 16)) & 0xffffu);
                    atomicAdd(&nxt[col >> 1], (int)((unsigned)bv << ((col & 1) << 4)));
                }
            }
            msgp[k][0] = nm0; msgp[k][1] = nm1; msgp[k][2] = nm2;
        }

        if (it >= 2) {
            if (__any(mism) && (tid & 63) == 0) atomicMax(&lastbad, it);
        }
        // reset rst -> u0 for the scatter two iterations from now (1x ds_write_b128)
        ((int4*)rst)[tid] = make_int4(u0a, u0b, u0c, u0d);

        __syncthreads();
        if (it >= 2 && lastbad < it) { conv_it = it - 1; break; }  // cur == l_v(it-1)

        int* t = cur; cur = nxt; nxt = rst; rst = t;       // rotate
    }

    // ---- if loop ran to completion, check parity of l_v(8) (now in cur) ----
    if (conv_it == 0) {
        int mism = 0;
        #pragma unroll
        for (int k = 0; k < RPT; ++k) {
            int par = 0;
            #pragma unroll
            for (int d = 0; d < RDEG; ++d) {
                const int col = (int)((colp[k][d >> 1] >> ((d & 1) * 16)) & 0xffffu);
                const int w = cur[col >> 1];
                const int l = (int)((w >> ((col & 1) << 4)) & 0xffff) - BIAS;
                par ^= (l <= 0) ? 1 : 0;
            }
            mism |= par ^ ((synbits >> k) & 1);
        }
        if (__any(mism) && (tid & 63) == 0) atomicMax(&lastbad, MAXIT + 1);
        __syncthreads();
        if (lastbad < MAXIT + 1) conv_it = MAXIT;
    }

    // ---- outputs: [e_out | num_iters | l_out | converges], float32 flat ----
    const int   num = conv_it ? conv_it : MAXIT;
    const float cv  = conv_it ? 1.0f : 0.0f;
    float* e_out   = out;
    float* num_out = out + (size_t)BB * NN;
    float* l_out   = num_out + BB;
    float* c_out   = l_out + (size_t)BB * NN;
    #pragma unroll
    for (int j = 0; j < 4; ++j) {
        const int w = tid + j * BLOCK;
        const int wv = cur[w];
        const int l0 = (wv & 0xffff) - BIAS;
        const int l1 = ((wv >> 16) & 0xffff) - BIAS;
        float2 e, l;
        e.x = (l0 <= 0) ? 1.0f : 0.0f;
        e.y = (l1 <= 0) ? 1.0f : 0.0f;
        l.x = (float)clamp8(l0) * 0.0625f;
        l.y = (float)clamp8(l1) * 0.0625f;
        ((float2*)(e_out + (size_t)b * NN))[w] = e;
        ((float2*)(l_out + (size_t)b * NN))[w] = l;
    }
    if (tid == 0) { num_out[b] = (float)num; c_out[b] = cv; }
}

extern "C" void kernel_launch(void* const* d_in, const int* in_sizes, int n_in,
                              void* d_out, int out_size, void* d_ws, size_t ws_size,
                              hipStream_t stream) {
    (void)in_sizes; (void)n_in; (void)d_ws; (void)ws_size; (void)out_size;
    const float* synd = (const float*)d_in[0];
    const float* llr0 = (const float*)d_in[1];
    const int*   Vcol = (const int*)d_in[3];   // V_c_col
    float*       out  = (float*)d_out;
    ldpc_kernel<<<BB, BLOCK, 0, stream>>>(synd, llr0, Vcol, out);
}